// Round 3
// baseline (388.447 us; speedup 1.0000x reference)
//
#include <hip/hip_runtime.h>
#include <hip/hip_bf16.h>

// Sizes (fixed by the problem)
#define NN 50000
#define GG 64
#define MM 16
#define FF 256
#define DD 512

// ---------------------------------------------------------------------------
// K_prep: fused. Blocks 0..255: A = Wq @ Wk^T [256x256] (16x16 tile each).
//         Block 256: collapse linear MLP -> Weff, then wv = Wv@Weff [256],
//                    beff (telescoped bias).
// ---------------------------------------------------------------------------
__global__ void k_prep(const float* __restrict__ Wq, const float* __restrict__ Wk,
                       const float* __restrict__ Wv,
                       const float* __restrict__ W1, const float* __restrict__ b1,
                       const float* __restrict__ W2, const float* __restrict__ b2,
                       const float* __restrict__ W3, const float* __restrict__ b3,
                       const float* __restrict__ W4, const float* __restrict__ b4,
                       float* __restrict__ A,
                       float* __restrict__ wv_out, float* __restrict__ beff_out) {
    int t = threadIdx.x;     // 256 threads
    if (blockIdx.x < 256) {
        // ---- A tile ----
        __shared__ float qs[16][132];   // +4 pad: bank-spread, 16B-aligned rows
        __shared__ float ks[16][132];
        int r = t >> 4, c = t & 15;
        int i0 = (blockIdx.x & 15) * 16, j0 = (blockIdx.x >> 4) * 16;
        float acc = 0.f;
        for (int d0 = 0; d0 < 512; d0 += 128) {
            for (int idx = t; idx < 16 * 128; idx += 256) {
                int rr = idx >> 7, cc = idx & 127;
                qs[rr][cc] = Wq[(i0 + rr) * 512 + d0 + cc];
                ks[rr][cc] = Wk[(j0 + rr) * 512 + d0 + cc];
            }
            __syncthreads();
            #pragma unroll 8
            for (int d = 0; d < 128; ++d) acc += qs[r][d] * ks[c][d];
            __syncthreads();
        }
        A[(i0 + r) * 256 + j0 + c] = acc;
    } else {
        // ---- MLP collapse ----
        __shared__ float w4[64];     // W4[:,0]
        __shared__ float t3[128];    // W3 @ W4
        __shared__ float t2[256];    // W2 @ t3
        __shared__ float we[512];    // W1 @ t2  (= Weff)
        if (t < 64) w4[t] = W4[t];
        __syncthreads();
        if (t < 128) {
            float s = 0.f;
            for (int j = 0; j < 64; ++j) s += W3[t * 64 + j] * w4[j];
            t3[t] = s;
        }
        __syncthreads();
        {
            float s = 0.f;
            for (int j = 0; j < 128; ++j) s += W2[t * 128 + j] * t3[j];
            t2[t] = s;
        }
        __syncthreads();
        for (int i = t; i < 512; i += 256) {
            float s = 0.f;
            for (int j = 0; j < 256; ++j) s += W1[i * 256 + j] * t2[j];
            we[i] = s;
        }
        __syncthreads();
        {   // wv[f] = Wv[f,:] . Weff
            float s = 0.f;
            for (int j = 0; j < 512; ++j) s += Wv[t * 512 + j] * we[j];
            wv_out[t] = s;
        }
        if (t == 0) {
            float s = b4[0];
            for (int j = 0; j < 64; ++j)  s += b3[j] * w4[j];
            for (int j = 0; j < 128; ++j) s += b2[j] * t3[j];
            for (int j = 0; j < 256; ++j) s += b1[j] * t2[j];
            *beff_out = s;
        }
    }
}

// ---------------------------------------------------------------------------
// K_group: per-group attention -> w[g,m].
//   B = factors[g] @ A            [16,256]
//   scores = B @ factors[g]^T     [16,16], key-mask n>=len -> -1e30
//   attn = softmax(scores, axis n)
//   vproj[n] = factors[g,n,:] . wv
//   w[g,m] = (sum_n attn[m,n]*vproj[n] + beff), zeroed for m>=len
// One block per group (64 blocks), 256 threads.
// ---------------------------------------------------------------------------
#define FS 260   // padded LDS row stride (floats); 260*4=1040 B (16B-aligned)

__global__ void k_group(const float* __restrict__ factors,
                        const int* __restrict__ lengths,
                        const float* __restrict__ A,
                        const float* __restrict__ wv,
                        const float* __restrict__ beffp,
                        float* __restrict__ w) {
    __shared__ float fs[16 * FS];
    __shared__ float bs[16 * FS];
    __shared__ float wvs[256];
    __shared__ float vproj[16];
    int g = blockIdx.x, t = threadIdx.x;

    for (int idx = t; idx < MM * FF; idx += 256)
        fs[(idx >> 8) * FS + (idx & 255)] = factors[g * (MM * FF) + idx];
    wvs[t] = wv[t];
    __syncthreads();

    // Phase 1: B = factors @ A. Thread t owns column j=t of B (all 16 rows).
    float acc[16];
    #pragma unroll
    for (int m = 0; m < 16; ++m) acc[m] = 0.f;
    for (int f0 = 0; f0 < 256; f0 += 4) {
        float a0 = A[(f0 + 0) * 256 + t];
        float a1 = A[(f0 + 1) * 256 + t];
        float a2 = A[(f0 + 2) * 256 + t];
        float a3 = A[(f0 + 3) * 256 + t];
        #pragma unroll
        for (int m = 0; m < 16; ++m) {
            float4 fm = *(const float4*)&fs[m * FS + f0];
            acc[m] += fm.x * a0 + fm.y * a1 + fm.z * a2 + fm.w * a3;
        }
    }
    #pragma unroll
    for (int m = 0; m < 16; ++m) bs[m * FS + t] = acc[m];
    __syncthreads();

    int m_ = t >> 4, n_ = t & 15;   // 16x16 thread layout

    // Phase 2: vproj[m_] = factors[g,m_,:].wv — 16-lane cooperative dot
    {
        float s = 0.f;
        #pragma unroll
        for (int q = 0; q < 16; ++q)
            s += fs[m_ * FS + n_ * 16 + q] * wvs[n_ * 16 + q];
        #pragma unroll
        for (int o = 8; o >= 1; o >>= 1) s += __shfl_xor(s, o, 16);
        if (n_ == 0) vproj[m_] = s;
    }
    __syncthreads();

    int len = lengths[g];

    // Phase 3: scores[m_][n_], masked softmax over n_, then w.
    float s = 0.f;
    for (int q = 0; q < 256; q += 4) {
        float4 bb = *(const float4*)&bs[m_ * FS + q];
        float4 ff = *(const float4*)&fs[n_ * FS + q];
        s += bb.x * ff.x + bb.y * ff.y + bb.z * ff.z + bb.w * ff.w;
    }
    if (n_ >= len) s = -1e30f;
    float mx = s;
    #pragma unroll
    for (int o = 8; o >= 1; o >>= 1) mx = fmaxf(mx, __shfl_xor(mx, o, 16));
    float p = expf(s - mx);
    float sm = p;
    #pragma unroll
    for (int o = 8; o >= 1; o >>= 1) sm += __shfl_xor(sm, o, 16);
    float attn = p / sm;
    float val = attn * vproj[n_];
    #pragma unroll
    for (int o = 8; o >= 1; o >>= 1) val += __shfl_xor(val, o, 16);
    if (n_ == 0) {
        float wr = val + beffp[0];
        if (m_ >= len) wr = 0.f;
        w[g * 16 + m_] = wr;
    }
}

// ---------------------------------------------------------------------------
// K_out: out[n,g] = raw[n,g,:].w[g,:] — the memory-bound streaming kernel.
// Grid-stride with stride % 64 == 0 so each thread's g is fixed; w row lives
// in 16 VGPRs. 4x float4 loads per output (wave covers contiguous 4 KB).
// ---------------------------------------------------------------------------
__global__ void k_out(const float* __restrict__ raw, const float* __restrict__ w,
                      float* __restrict__ out, int total) {
    int tid = blockIdx.x * blockDim.x + threadIdx.x;
    int stride = gridDim.x * blockDim.x;      // 2048*256, multiple of 64
    int g = tid & 63;
    const float4* wp = (const float4*)&w[g * 16];
    float4 w0 = wp[0], w1 = wp[1], w2 = wp[2], w3 = wp[3];
    for (int p = tid; p < total; p += stride) {
        const float4* r = (const float4*)&raw[(size_t)p * 16];
        float4 r0 = r[0], r1 = r[1], r2 = r[2], r3 = r[3];
        float s = r0.x * w0.x + r0.y * w0.y + r0.z * w0.z + r0.w * w0.w
                + r1.x * w1.x + r1.y * w1.y + r1.z * w1.z + r1.w * w1.w
                + r2.x * w2.x + r2.y * w2.y + r2.z * w2.z + r2.w * w2.w
                + r3.x * w3.x + r3.y * w3.y + r3.z * w3.z + r3.w * w3.w;
        out[p] = s;
    }
}

// ---------------------------------------------------------------------------
extern "C" void kernel_launch(void* const* d_in, const int* in_sizes, int n_in,
                              void* d_out, int out_size, void* d_ws, size_t ws_size,
                              hipStream_t stream) {
    const float* raw     = (const float*)d_in[0];
    const float* factors = (const float*)d_in[1];
    const int*   lengths = (const int*)  d_in[2];
    const float* Wq      = (const float*)d_in[3];
    const float* Wk      = (const float*)d_in[4];
    const float* Wv      = (const float*)d_in[5];
    const float* W1      = (const float*)d_in[6];
    const float* b1      = (const float*)d_in[7];
    const float* W2      = (const float*)d_in[8];
    const float* b2      = (const float*)d_in[9];
    const float* W3      = (const float*)d_in[10];
    const float* b3      = (const float*)d_in[11];
    const float* W4      = (const float*)d_in[12];
    const float* b4      = (const float*)d_in[13];
    float* out = (float*)d_out;

    // Workspace layout (floats)
    float* ws   = (float*)d_ws;
    float* A    = ws;             // 65536
    float* wv   = ws + 65536;     // 256
    float* beff = ws + 65792;     // 1
    float* w    = ws + 65808;     // 1024 (16-float aligned)

    k_prep<<<257, 256, 0, stream>>>(Wq, Wk, Wv, W1, b1, W2, b2, W3, b3, W4, b4,
                                    A, wv, beff);
    k_group<<<GG, 256, 0, stream>>>(factors, lengths, A, wv, beff, w);

    int total = NN * GG;
    k_out<<<2048, 256, 0, stream>>>(raw, w, out, total);
}